// Round 3
// baseline (1030.319 us; speedup 1.0000x reference)
//
#include <hip/hip_runtime.h>
#include <hip/hip_bf16.h>
#include <stdint.h>

#define DIMN 2048
#define KVD  512
#define NH   32
#define BATCH 2
#define SEQ  2048
#define ROWS (BATCH*SEQ)   // 4096

typedef __attribute__((ext_vector_type(4))) float f32x4;
typedef __attribute__((ext_vector_type(8))) short bf16x8;

__device__ __forceinline__ float bf2f(short s){
  union{uint32_t u;float f;} v; v.u=((uint32_t)(uint16_t)s)<<16; return v.f;
}
__device__ __forceinline__ short f2bf(float f){
  union{float f;uint32_t u;} v; v.f=f;
  uint32_t r=(v.u + 0x7fffu + ((v.u>>16)&1u))>>16; return (short)r;
}
__device__ __forceinline__ f32x4 mfma16(bf16x8 a, bf16x8 b, f32x4 c){
  return __builtin_amdgcn_mfma_f32_16x16x32_bf16(a,b,c,0,0,0);
}
__device__ __forceinline__ short ternbf(float v, float thr){
  // {-1,0,1} as bf16 bit patterns (exact)
  return v > thr ? (short)0x3F80 : (v < -thr ? (short)0xBF80 : (short)0);
}

// ---------------- abs-mean reduction (deterministic, two stage) ----------------
__global__ void k_abssum(const float* __restrict__ w, int n, float* __restrict__ partial){
  __shared__ float red[256];
  float s = 0.f;
  for (int i = blockIdx.x*256 + threadIdx.x; i < n; i += 256*gridDim.x) s += fabsf(w[i]);
  red[threadIdx.x] = s; __syncthreads();
  for (int o = 128; o > 0; o >>= 1){
    if (threadIdx.x < o) red[threadIdx.x] += red[threadIdx.x+o];
    __syncthreads();
  }
  if (threadIdx.x == 0) partial[blockIdx.x] = red[0];
}

__global__ void k_scales(const float* __restrict__ partial, float* __restrict__ scales){
  __shared__ float red[256];
  int t = threadIdx.x;
  const int counts[4] = {DIMN*DIMN, KVD*DIMN, KVD*DIMN, DIMN*DIMN};
  for (int wi = 0; wi < 4; wi++){
    red[t] = partial[wi*256 + t]; __syncthreads();
    for (int o = 128; o > 0; o >>= 1){
      if (t < o) red[t] += red[t+o];
      __syncthreads();
    }
    if (t == 0){
      float mean = red[0] / (float)counts[wi];
      scales[wi] = 0.05f * fmaxf(mean, 1e-6f);   // store threshold directly
    }
    __syncthreads();
  }
}

// ---------------- QKV GEMM:  O = split(X) * tern(W)^T ----------------
// X: [M,K] f32 row-major (split to hi/lo bf16 during staging)
// W: [N,K] f32 row-major (ternarized to bf16 during staging)
// Output: hi/lo bf16 split (lo only if WRITELO).
template<int WRITELO>
__global__ __launch_bounds__(256) void k_gemm_qkv(
    const float* __restrict__ X, const float* __restrict__ W,
    const float* __restrict__ scales, int wi,
    short* __restrict__ Oh, short* __restrict__ Ol,
    int M, int N, int K){
  __shared__ short Ah[64][40];
  __shared__ short Al[64][40];
  __shared__ short Bs[64][40];
  const float thr = scales[wi];
  const int bn = blockIdx.x*64, bm = blockIdx.y*64;
  const int tid = threadIdx.x, lane = tid & 63, w = tid >> 6;
  const int wr = w >> 1, wc = w & 1;
  const int r0 = wr*32, c0 = wc*32;
  const int la = lane & 15, kg = lane >> 4;
  const int srow = tid >> 2, scg = tid & 3;
  f32x4 acc[2][2] = {};
  for (int k0 = 0; k0 < K; k0 += 32){
    // stage A: load 8 f32, split hi/lo
    {
      const float* xs = X + (long)(bm+srow)*K + k0 + scg*8;
      f32x4 x0 = *(const f32x4*)xs;
      f32x4 x1 = *(const f32x4*)(xs + 4);
      bf16x8 h, l;
      #pragma unroll
      for (int i = 0; i < 4; i++){
        short hh = f2bf(x0[i]); h[i] = hh; l[i] = f2bf(x0[i] - bf2f(hh));
        short h2 = f2bf(x1[i]); h[4+i] = h2; l[4+i] = f2bf(x1[i] - bf2f(h2));
      }
      *(bf16x8*)&Ah[srow][scg*8] = h;
      *(bf16x8*)&Al[srow][scg*8] = l;
    }
    // stage B: load 8 f32, ternarize
    {
      const float* wsrc = W + (long)(bn+srow)*K + k0 + scg*8;
      f32x4 w0 = *(const f32x4*)wsrc;
      f32x4 w1 = *(const f32x4*)(wsrc + 4);
      bf16x8 t;
      #pragma unroll
      for (int i = 0; i < 4; i++){
        t[i]   = ternbf(w0[i], thr);
        t[4+i] = ternbf(w1[i], thr);
      }
      *(bf16x8*)&Bs[srow][scg*8] = t;
    }
    __syncthreads();
    bf16x8 a0 = *(bf16x8*)&Ah[r0+la][kg*8];
    bf16x8 a1 = *(bf16x8*)&Ah[r0+16+la][kg*8];
    bf16x8 l0 = *(bf16x8*)&Al[r0+la][kg*8];
    bf16x8 l1 = *(bf16x8*)&Al[r0+16+la][kg*8];
    bf16x8 b0 = *(bf16x8*)&Bs[c0+la][kg*8];
    bf16x8 b1 = *(bf16x8*)&Bs[c0+16+la][kg*8];
    acc[0][0] = mfma16(a0,b0,acc[0][0]);
    acc[0][1] = mfma16(a0,b1,acc[0][1]);
    acc[1][0] = mfma16(a1,b0,acc[1][0]);
    acc[1][1] = mfma16(a1,b1,acc[1][1]);
    acc[0][0] = mfma16(l0,b0,acc[0][0]);
    acc[0][1] = mfma16(l0,b1,acc[0][1]);
    acc[1][0] = mfma16(l1,b0,acc[1][0]);
    acc[1][1] = mfma16(l1,b1,acc[1][1]);
    __syncthreads();
  }
  for (int mi = 0; mi < 2; mi++)
    for (int ni = 0; ni < 2; ni++)
      for (int rr = 0; rr < 4; rr++){
        long row = bm + r0 + mi*16 + kg*4 + rr;
        long col = bn + c0 + ni*16 + la;
        float v = acc[mi][ni][rr];
        short h = f2bf(v);
        Oh[row*(long)N + col] = h;
        if constexpr (WRITELO)
          Ol[row*(long)N + col] = f2bf(v - bf2f(h));
      }
}

// ---------------- Output GEMM:  Of = A_bf16 * tern(W)^T  (f32 out) ----------------
__global__ __launch_bounds__(256) void k_gemm_out(
    const short* __restrict__ A, const float* __restrict__ W,
    const float* __restrict__ scales, int wi,
    float* __restrict__ Of, int M, int N, int K){
  __shared__ short As[64][40];
  __shared__ short Bs[64][40];
  const float thr = scales[wi];
  const int bn = blockIdx.x*64, bm = blockIdx.y*64;
  const int tid = threadIdx.x, lane = tid & 63, w = tid >> 6;
  const int wr = w >> 1, wc = w & 1;
  const int r0 = wr*32, c0 = wc*32;
  const int la = lane & 15, kg = lane >> 4;
  const int srow = tid >> 2, scg = tid & 3;
  f32x4 acc[2][2] = {};
  for (int k0 = 0; k0 < K; k0 += 32){
    *(bf16x8*)&As[srow][scg*8] = *(const bf16x8*)(A + (long)(bm+srow)*K + k0 + scg*8);
    {
      const float* wsrc = W + (long)(bn+srow)*K + k0 + scg*8;
      f32x4 w0 = *(const f32x4*)wsrc;
      f32x4 w1 = *(const f32x4*)(wsrc + 4);
      bf16x8 t;
      #pragma unroll
      for (int i = 0; i < 4; i++){
        t[i]   = ternbf(w0[i], thr);
        t[4+i] = ternbf(w1[i], thr);
      }
      *(bf16x8*)&Bs[srow][scg*8] = t;
    }
    __syncthreads();
    bf16x8 a0 = *(bf16x8*)&As[r0+la][kg*8];
    bf16x8 a1 = *(bf16x8*)&As[r0+16+la][kg*8];
    bf16x8 b0 = *(bf16x8*)&Bs[c0+la][kg*8];
    bf16x8 b1 = *(bf16x8*)&Bs[c0+16+la][kg*8];
    acc[0][0] = mfma16(a0,b0,acc[0][0]);
    acc[0][1] = mfma16(a0,b1,acc[0][1]);
    acc[1][0] = mfma16(a1,b0,acc[1][0]);
    acc[1][1] = mfma16(a1,b1,acc[1][1]);
    __syncthreads();
  }
  for (int mi = 0; mi < 2; mi++)
    for (int ni = 0; ni < 2; ni++)
      for (int rr = 0; rr < 4; rr++){
        long row = bm + r0 + mi*16 + kg*4 + rr;
        long col = bn + c0 + ni*16 + la;
        Of[row*(long)N + col] = acc[mi][ni][rr];
      }
}

// ---------------- GQA causal flash attention ----------------
// grid: (qtile=SEQ/64, head=32, batch=2). 256 threads = 4 waves; wave w owns q rows w*16..w*16+15.
// Scores use 3-MFMA split (qhi*khi + qhi*klo + qlo*khi) for fp32-class accuracy.
__global__ __launch_bounds__(256) void k_attn(
    const short* __restrict__ qhi, const short* __restrict__ qlo,
    const short* __restrict__ khi, const short* __restrict__ klo,
    const short* __restrict__ vhi, short* __restrict__ attout){
  __shared__ short Vt[64][80];   // V transposed: Vt[d][kv]
  __shared__ short P[64][80];    // probs tile (per-wave private rows)
  const int qt = blockIdx.x, h = blockIdx.y, b = blockIdx.z;
  const int g = h >> 2;
  const int tid = threadIdx.x, w = tid >> 6, lane = tid & 63;
  const int la = lane & 15, kg = lane >> 4;
  const int qbase = qt*64;

  // Q fragments (A-operand: lane holds row la, k = kg*8..)
  bf16x8 qh[2], ql[2];
  {
    long qrow = (long)(b*SEQ + qbase + w*16 + la);
    for (int ks = 0; ks < 2; ks++){
      long off = qrow*DIMN + h*64 + ks*32 + kg*8;
      qh[ks] = *(const bf16x8*)(qhi + off);
      ql[ks] = *(const bf16x8*)(qlo + off);
    }
  }
  f32x4 Oacc[4] = {};
  float m[4], l[4];
  for (int r = 0; r < 4; r++){ m[r] = -INFINITY; l[r] = 0.f; }

  const int nkt = qt + 1;  // causal tile skip
  for (int kt = 0; kt < nkt; kt++){
    __syncthreads();
    // stage V transposed
    {
      int kk = tid >> 2, dg = tid & 3;
      long vrow = (long)(b*SEQ + kt*64 + kk)*KVD + g*64 + dg*16;
      bf16x8 v0 = *(const bf16x8*)(vhi + vrow);
      bf16x8 v1 = *(const bf16x8*)(vhi + vrow + 8);
      #pragma unroll
      for (int i = 0; i < 8; i++){
        Vt[dg*16 + i][kk]     = v0[i];
        Vt[dg*16 + 8 + i][kk] = v1[i];
      }
    }
    __syncthreads();

    // scores: S[q][kc], 4 col-tiles of 16
    f32x4 s[4];
    #pragma unroll
    for (int ni = 0; ni < 4; ni++){
      f32x4 a = {0.f,0.f,0.f,0.f};
      #pragma unroll
      for (int ks = 0; ks < 2; ks++){
        long krow = (long)(b*SEQ + kt*64 + ni*16 + la)*KVD + g*64 + ks*32 + kg*8;
        bf16x8 kh = *(const bf16x8*)(khi + krow);
        bf16x8 kl = *(const bf16x8*)(klo + krow);
        a = mfma16(qh[ks], kh, a);
        a = mfma16(qh[ks], kl, a);
        a = mfma16(ql[ks], kh, a);
      }
      s[ni] = a;
    }

    // scale + causal mask (only diagonal tile needs masking)
    const bool lastTile = (kt == qt);
    #pragma unroll
    for (int ni = 0; ni < 4; ni++)
      #pragma unroll
      for (int r = 0; r < 4; r++){
        float v = s[ni][r] * 0.125f;
        if (lastTile){
          int kc = kt*64 + ni*16 + la;
          int qr = qbase + w*16 + kg*4 + r;
          if (kc > qr) v = -INFINITY;
        }
        s[ni][r] = v;
      }

    // online softmax (row reduce across 16 lanes in group)
    float ef[4];
    #pragma unroll
    for (int r = 0; r < 4; r++){
      float v = fmaxf(fmaxf(s[0][r], s[1][r]), fmaxf(s[2][r], s[3][r]));
      for (int o = 1; o < 16; o <<= 1) v = fmaxf(v, __shfl_xor(v, o, 64));
      float mn = fmaxf(m[r], v);
      ef[r] = __expf(m[r] - mn);
      m[r] = mn;
    }
    #pragma unroll
    for (int r = 0; r < 4; r++){
      float rs = 0.f;
      #pragma unroll
      for (int ni = 0; ni < 4; ni++){
        float p = __expf(s[ni][r] - m[r]);
        s[ni][r] = p;
        rs += p;
      }
      for (int o = 1; o < 16; o <<= 1) rs += __shfl_xor(rs, o, 64);
      l[r] = l[r]*ef[r] + rs;
    }
    #pragma unroll
    for (int d = 0; d < 4; d++)
      #pragma unroll
      for (int r = 0; r < 4; r++) Oacc[d][r] *= ef[r];

    // P -> LDS (bf16), then read back as A-fragments (same wave, ds-ordered)
    #pragma unroll
    for (int ni = 0; ni < 4; ni++)
      #pragma unroll
      for (int r = 0; r < 4; r++)
        P[w*16 + kg*4 + r][ni*16 + la] = f2bf(s[ni][r]);
    #pragma unroll
    for (int ks = 0; ks < 2; ks++){
      bf16x8 pa = *(bf16x8*)&P[w*16 + la][ks*32 + kg*8];
      #pragma unroll
      for (int d = 0; d < 4; d++){
        bf16x8 vb = *(bf16x8*)&Vt[d*16 + la][ks*32 + kg*8];
        Oacc[d] = mfma16(pa, vb, Oacc[d]);
      }
    }
  }

  // finalize: O /= l, write bf16
  #pragma unroll
  for (int d = 0; d < 4; d++)
    #pragma unroll
    for (int r = 0; r < 4; r++){
      float v = Oacc[d][r] / l[r];
      long row = (long)(b*SEQ + qbase + w*16 + kg*4 + r);
      attout[row*DIMN + h*64 + d*16 + la] = f2bf(v);
    }
}

// ---------------- host ----------------
extern "C" void kernel_launch(void* const* d_in, const int* in_sizes, int n_in,
                              void* d_out, int out_size, void* d_ws, size_t ws_size,
                              hipStream_t stream){
  const float* x  = (const float*)d_in[0];
  const float* wq = (const float*)d_in[1];
  const float* wk = (const float*)d_in[2];
  const float* wv = (const float*)d_in[3];
  const float* wo = (const float*)d_in[4];
  float* out = (float*)d_out;
  char* ws = (char*)d_ws;

  // workspace layout (60.07 MB total)
  const size_t SZ_QD = (size_t)ROWS*DIMN*2;  // 16 MB
  const size_t SZ_KD = (size_t)ROWS*KVD*2;   // 4 MB
  const size_t NEED = 65536 + 2*SZ_QD + 3*SZ_KD + SZ_QD;
  if (ws_size < NEED) return;  // clean diagnostic failure instead of OOB fault

  float* scales   = (float*)ws;            // 4 floats
  float* partials = (float*)(ws + 1024);   // 4 x 256 floats
  size_t off = 65536;
  auto alloc = [&](size_t bytes)->char*{
    char* p = ws + off; off += (bytes + 255) & ~(size_t)255; return p;
  };
  short* qhib = (short*)alloc(SZ_QD);
  short* qlob = (short*)alloc(SZ_QD);
  short* khib = (short*)alloc(SZ_KD);
  short* klob = (short*)alloc(SZ_KD);
  short* vhib = (short*)alloc(SZ_KD);
  short* atto = (short*)alloc(SZ_QD);

  // 1) weight thresholds (deterministic two-stage abs-mean)
  k_abssum<<<256,256,0,stream>>>(wq, DIMN*DIMN, partials + 0);
  k_abssum<<<256,256,0,stream>>>(wk, KVD*DIMN,  partials + 256);
  k_abssum<<<256,256,0,stream>>>(wv, KVD*DIMN,  partials + 512);
  k_abssum<<<256,256,0,stream>>>(wo, DIMN*DIMN, partials + 768);
  k_scales<<<1,256,0,stream>>>(partials, scales);

  // 2) Q/K/V GEMMs (x split + W ternarize fused into staging)
  {
    dim3 g(DIMN/64, ROWS/64);
    k_gemm_qkv<1><<<g,256,0,stream>>>(x, wq, scales, 0, qhib, qlob, ROWS, DIMN, DIMN);
  }
  {
    dim3 g(KVD/64, ROWS/64);
    k_gemm_qkv<1><<<g,256,0,stream>>>(x, wk, scales, 1, khib, klob, ROWS, KVD, DIMN);
    k_gemm_qkv<0><<<g,256,0,stream>>>(x, wv, scales, 2, vhib, nullptr, ROWS, KVD, DIMN);
  }

  // 3) attention
  {
    dim3 g(SEQ/64, NH, BATCH);
    k_attn<<<g,256,0,stream>>>(qhib, qlob, khib, klob, vhib, atto);
  }

  // 4) output GEMM -> f32
  {
    dim3 g(DIMN/64, ROWS/64);
    k_gemm_out<<<g,256,0,stream>>>(atto, wo, scales, 3, out, ROWS, DIMN, DIMN);
  }
}

// Round 4
// 856.634 us; speedup vs baseline: 1.2028x; 1.2028x over previous
//
#include <hip/hip_runtime.h>
#include <hip/hip_bf16.h>
#include <stdint.h>

#define DIMN 2048
#define KVD  512
#define NH   32
#define BATCH 2
#define SEQ  2048
#define ROWS (BATCH*SEQ)   // 4096
#define NT   (SEQ/64)      // 32 k/q tiles of 64

typedef __attribute__((ext_vector_type(4))) float f32x4;
typedef __attribute__((ext_vector_type(8))) short bf16x8;

__device__ __forceinline__ float bf2f(short s){
  union{uint32_t u;float f;} v; v.u=((uint32_t)(uint16_t)s)<<16; return v.f;
}
__device__ __forceinline__ short f2bf(float f){
  union{float f;uint32_t u;} v; v.f=f;
  uint32_t r=(v.u + 0x7fffu + ((v.u>>16)&1u))>>16; return (short)r;
}
__device__ __forceinline__ f32x4 mfma16(bf16x8 a, bf16x8 b, f32x4 c){
  return __builtin_amdgcn_mfma_f32_16x16x32_bf16(a,b,c,0,0,0);
}
__device__ __forceinline__ short ternbf(float v, float thr){
  return v > thr ? (short)0x3F80 : (v < -thr ? (short)0xBF80 : (short)0);
}

// ---------------- abs-mean reduction (deterministic, two stage, fused 4 weights) --------
__global__ void k_abssum4(const float* __restrict__ w0, const float* __restrict__ w1,
                          const float* __restrict__ w2, const float* __restrict__ w3,
                          float* __restrict__ partial){
  __shared__ float red[256];
  const float* ptrs[4] = {w0, w1, w2, w3};
  const int ns[4] = {DIMN*DIMN, KVD*DIMN, KVD*DIMN, DIMN*DIMN};
  const int wi = blockIdx.y;
  const float* w = ptrs[wi];
  const int n = ns[wi];
  float s = 0.f;
  for (int i = blockIdx.x*256 + threadIdx.x; i < n; i += 256*gridDim.x) s += fabsf(w[i]);
  red[threadIdx.x] = s; __syncthreads();
  for (int o = 128; o > 0; o >>= 1){
    if (threadIdx.x < o) red[threadIdx.x] += red[threadIdx.x+o];
    __syncthreads();
  }
  if (threadIdx.x == 0) partial[wi*256 + blockIdx.x] = red[0];
}

__global__ void k_scales(const float* __restrict__ partial, float* __restrict__ scales){
  __shared__ float red[256];
  int t = threadIdx.x;
  const int counts[4] = {DIMN*DIMN, KVD*DIMN, KVD*DIMN, DIMN*DIMN};
  for (int wi = 0; wi < 4; wi++){
    red[t] = partial[wi*256 + t]; __syncthreads();
    for (int o = 128; o > 0; o >>= 1){
      if (t < o) red[t] += red[t+o];
      __syncthreads();
    }
    if (t == 0){
      float mean = red[0] / (float)counts[wi];
      scales[wi] = 0.05f * fmaxf(mean, 1e-6f);
    }
    __syncthreads();
  }
}

// ---------------- QKV GEMM (128x128 tile):  O = split(X) * tern(W)^T ----------------
// X: [M,K] f32 (split hi/lo bf16 in staging); W: [N,K] f32 (ternarized in staging).
template<int WRITELO>
__global__ __launch_bounds__(256) void k_gemm_qkv(
    const float* __restrict__ X, const float* __restrict__ W,
    const float* __restrict__ scales, int wi,
    short* __restrict__ Oh, short* __restrict__ Ol,
    int M, int N, int K){
  __shared__ short Ah[128][40];
  __shared__ short Al[128][40];
  __shared__ short Bs[128][40];
  const float thr = scales[wi];
  const int bn = blockIdx.x*128, bm = blockIdx.y*128;
  const int tid = threadIdx.x, lane = tid & 63, w = tid >> 6;
  const int wr = w >> 1, wc = w & 1;
  const int la = lane & 15, kg = lane >> 4;
  const int srow = tid >> 1, sc = (tid & 1) * 16;
  f32x4 acc[4][4] = {};
  for (int k0 = 0; k0 < K; k0 += 32){
    // stage A: 16 f32 -> hi/lo bf16
    {
      const float* xs = X + (long)(bm+srow)*K + k0 + sc;
      f32x4 xv0 = *(const f32x4*)xs;
      f32x4 xv1 = *(const f32x4*)(xs+4);
      f32x4 xv2 = *(const f32x4*)(xs+8);
      f32x4 xv3 = *(const f32x4*)(xs+12);
      bf16x8 h0, l0, h1, l1;
      #pragma unroll
      for (int i = 0; i < 4; i++){
        short a = f2bf(xv0[i]); h0[i]   = a; l0[i]   = f2bf(xv0[i]-bf2f(a));
        short b = f2bf(xv1[i]); h0[4+i] = b; l0[4+i] = f2bf(xv1[i]-bf2f(b));
        short c = f2bf(xv2[i]); h1[i]   = c; l1[i]   = f2bf(xv2[i]-bf2f(c));
        short d = f2bf(xv3[i]); h1[4+i] = d; l1[4+i] = f2bf(xv3[i]-bf2f(d));
      }
      *(bf16x8*)&Ah[srow][sc]   = h0;  *(bf16x8*)&Ah[srow][sc+8] = h1;
      *(bf16x8*)&Al[srow][sc]   = l0;  *(bf16x8*)&Al[srow][sc+8] = l1;
    }
    // stage B: 16 f32 -> ternary bf16
    {
      const float* wsrc = W + (long)(bn+srow)*K + k0 + sc;
      f32x4 wv0 = *(const f32x4*)wsrc;
      f32x4 wv1 = *(const f32x4*)(wsrc+4);
      f32x4 wv2 = *(const f32x4*)(wsrc+8);
      f32x4 wv3 = *(const f32x4*)(wsrc+12);
      bf16x8 t0, t1;
      #pragma unroll
      for (int i = 0; i < 4; i++){
        t0[i]   = ternbf(wv0[i], thr);
        t0[4+i] = ternbf(wv1[i], thr);
        t1[i]   = ternbf(wv2[i], thr);
        t1[4+i] = ternbf(wv3[i], thr);
      }
      *(bf16x8*)&Bs[srow][sc]   = t0;  *(bf16x8*)&Bs[srow][sc+8] = t1;
    }
    __syncthreads();
    bf16x8 af[4], alf[4], bfr[4];
    #pragma unroll
    for (int mi = 0; mi < 4; mi++){
      af[mi]  = *(bf16x8*)&Ah[wr*64 + mi*16 + la][kg*8];
      alf[mi] = *(bf16x8*)&Al[wr*64 + mi*16 + la][kg*8];
    }
    #pragma unroll
    for (int ni = 0; ni < 4; ni++)
      bfr[ni] = *(bf16x8*)&Bs[wc*64 + ni*16 + la][kg*8];
    #pragma unroll
    for (int mi = 0; mi < 4; mi++)
      #pragma unroll
      for (int ni = 0; ni < 4; ni++){
        acc[mi][ni] = mfma16(af[mi],  bfr[ni], acc[mi][ni]);
        acc[mi][ni] = mfma16(alf[mi], bfr[ni], acc[mi][ni]);
      }
    __syncthreads();
  }
  #pragma unroll
  for (int mi = 0; mi < 4; mi++)
    #pragma unroll
    for (int ni = 0; ni < 4; ni++)
      #pragma unroll
      for (int rr = 0; rr < 4; rr++){
        long row = bm + wr*64 + mi*16 + kg*4 + rr;
        long col = bn + wc*64 + ni*16 + la;
        float v = acc[mi][ni][rr];
        short hb = f2bf(v);
        Oh[row*(long)N + col] = hb;
        if constexpr (WRITELO)
          Ol[row*(long)N + col] = f2bf(v - bf2f(hb));
      }
}

// ---------------- Output GEMM (128x128 tile):  Of = A_bf16 * tern(W)^T ----------------
__global__ __launch_bounds__(256) void k_gemm_out(
    const short* __restrict__ A, const float* __restrict__ W,
    const float* __restrict__ scales, int wi,
    float* __restrict__ Of, int M, int N, int K){
  __shared__ short As[128][40];
  __shared__ short Bs[128][40];
  const float thr = scales[wi];
  const int bn = blockIdx.x*128, bm = blockIdx.y*128;
  const int tid = threadIdx.x, lane = tid & 63, w = tid >> 6;
  const int wr = w >> 1, wc = w & 1;
  const int la = lane & 15, kg = lane >> 4;
  const int srow = tid >> 1, sc = (tid & 1) * 16;
  f32x4 acc[4][4] = {};
  for (int k0 = 0; k0 < K; k0 += 32){
    *(bf16x8*)&As[srow][sc]   = *(const bf16x8*)(A + (long)(bm+srow)*K + k0 + sc);
    *(bf16x8*)&As[srow][sc+8] = *(const bf16x8*)(A + (long)(bm+srow)*K + k0 + sc + 8);
    {
      const float* wsrc = W + (long)(bn+srow)*K + k0 + sc;
      f32x4 wv0 = *(const f32x4*)wsrc;
      f32x4 wv1 = *(const f32x4*)(wsrc+4);
      f32x4 wv2 = *(const f32x4*)(wsrc+8);
      f32x4 wv3 = *(const f32x4*)(wsrc+12);
      bf16x8 t0, t1;
      #pragma unroll
      for (int i = 0; i < 4; i++){
        t0[i]   = ternbf(wv0[i], thr);
        t0[4+i] = ternbf(wv1[i], thr);
        t1[i]   = ternbf(wv2[i], thr);
        t1[4+i] = ternbf(wv3[i], thr);
      }
      *(bf16x8*)&Bs[srow][sc]   = t0;  *(bf16x8*)&Bs[srow][sc+8] = t1;
    }
    __syncthreads();
    bf16x8 af[4], bfr[4];
    #pragma unroll
    for (int mi = 0; mi < 4; mi++)
      af[mi] = *(bf16x8*)&As[wr*64 + mi*16 + la][kg*8];
    #pragma unroll
    for (int ni = 0; ni < 4; ni++)
      bfr[ni] = *(bf16x8*)&Bs[wc*64 + ni*16 + la][kg*8];
    #pragma unroll
    for (int mi = 0; mi < 4; mi++)
      #pragma unroll
      for (int ni = 0; ni < 4; ni++)
        acc[mi][ni] = mfma16(af[mi], bfr[ni], acc[mi][ni]);
    __syncthreads();
  }
  #pragma unroll
  for (int mi = 0; mi < 4; mi++)
    #pragma unroll
    for (int ni = 0; ni < 4; ni++)
      #pragma unroll
      for (int rr = 0; rr < 4; rr++){
        long row = bm + wr*64 + mi*16 + kg*4 + rr;
        long col = bn + wc*64 + ni*16 + la;
        Of[row*(long)N + col] = acc[mi][ni][rr];
      }
}

// ---------------- GQA causal flash attention (balanced pairing) ----------------
// grid: (NT/2=16, head=32, batch=2). Block qp processes q-tiles {qp, NT-1-qp}
// -> every block does exactly NT+1 = 33 k-tiles of work (uniform).
// Scores use 3-MFMA split (qhi*khi + qhi*klo + qlo*khi) for fp32-class accuracy.
__global__ __launch_bounds__(256) void k_attn(
    const short* __restrict__ qhi, const short* __restrict__ qlo,
    const short* __restrict__ khi, const short* __restrict__ klo,
    const short* __restrict__ vhi, short* __restrict__ attout){
  __shared__ short Vt[64][72];   // V transposed: Vt[d][kv]  (pad 72: 2-way max)
  __shared__ short P[64][72];    // probs tile
  const int qp = blockIdx.x, h = blockIdx.y, b = blockIdx.z;
  const int g = h >> 2;
  const int tid = threadIdx.x, w = tid >> 6, lane = tid & 63;
  const int la = lane & 15, kg = lane >> 4;

  for (int phase = 0; phase < 2; phase++){
    const int qt = phase ? (NT - 1 - qp) : qp;
    const int qbase = qt*64;

    bf16x8 qh[2], ql[2];
    {
      long qrow = (long)(b*SEQ + qbase + w*16 + la);
      #pragma unroll
      for (int ks = 0; ks < 2; ks++){
        long off = qrow*DIMN + h*64 + ks*32 + kg*8;
        qh[ks] = *(const bf16x8*)(qhi + off);
        ql[ks] = *(const bf16x8*)(qlo + off);
      }
    }
    f32x4 Oacc[4] = {};
    float m[4], l[4];
    #pragma unroll
    for (int r = 0; r < 4; r++){ m[r] = -INFINITY; l[r] = 0.f; }

    for (int kt = 0; kt <= qt; kt++){
      __syncthreads();
      // stage V transposed
      {
        int kk = tid >> 2, dg = tid & 3;
        long vrow = (long)(b*SEQ + kt*64 + kk)*KVD + g*64 + dg*16;
        bf16x8 v0 = *(const bf16x8*)(vhi + vrow);
        bf16x8 v1 = *(const bf16x8*)(vhi + vrow + 8);
        #pragma unroll
        for (int i = 0; i < 8; i++){
          Vt[dg*16 + i][kk]     = v0[i];
          Vt[dg*16 + 8 + i][kk] = v1[i];
        }
      }
      __syncthreads();

      // scores
      f32x4 s[4];
      #pragma unroll
      for (int ni = 0; ni < 4; ni++){
        f32x4 a = {0.f,0.f,0.f,0.f};
        #pragma unroll
        for (int ks = 0; ks < 2; ks++){
          long krow = (long)(b*SEQ + kt*64 + ni*16 + la)*KVD + g*64 + ks*32 + kg*8;
          bf16x8 kh = *(const bf16x8*)(khi + krow);
          bf16x8 kl = *(const bf16x8*)(klo + krow);
          a = mfma16(qh[ks], kh, a);
          a = mfma16(qh[ks], kl, a);
          a = mfma16(ql[ks], kh, a);
        }
        s[ni] = a;
      }

      const bool lastTile = (kt == qt);
      #pragma unroll
      for (int ni = 0; ni < 4; ni++)
        #pragma unroll
        for (int r = 0; r < 4; r++){
          float v = s[ni][r] * 0.125f;
          if (lastTile){
            int kc = kt*64 + ni*16 + la;
            int qr = qbase + w*16 + kg*4 + r;
            if (kc > qr) v = -INFINITY;
          }
          s[ni][r] = v;
        }

      // online softmax
      float ef[4];
      #pragma unroll
      for (int r = 0; r < 4; r++){
        float v = fmaxf(fmaxf(s[0][r], s[1][r]), fmaxf(s[2][r], s[3][r]));
        for (int o = 1; o < 16; o <<= 1) v = fmaxf(v, __shfl_xor(v, o, 64));
        float mn = fmaxf(m[r], v);
        ef[r] = __expf(m[r] - mn);
        m[r] = mn;
      }
      #pragma unroll
      for (int r = 0; r < 4; r++){
        float rs = 0.f;
        #pragma unroll
        for (int ni = 0; ni < 4; ni++){
          float p = __expf(s[ni][r] - m[r]);
          s[ni][r] = p;
          rs += p;
        }
        for (int o = 1; o < 16; o <<= 1) rs += __shfl_xor(rs, o, 64);
        l[r] = l[r]*ef[r] + rs;
      }
      #pragma unroll
      for (int d = 0; d < 4; d++)
        #pragma unroll
        for (int r = 0; r < 4; r++) Oacc[d][r] *= ef[r];

      // P -> LDS bf16, read back as A-fragments
      #pragma unroll
      for (int ni = 0; ni < 4; ni++)
        #pragma unroll
        for (int r = 0; r < 4; r++)
          P[w*16 + kg*4 + r][ni*16 + la] = f2bf(s[ni][r]);
      #pragma unroll
      for (int ks = 0; ks < 2; ks++){
        bf16x8 pa = *(bf16x8*)&P[w*16 + la][ks*32 + kg*8];
        #pragma unroll
        for (int d = 0; d < 4; d++){
          bf16x8 vb = *(bf16x8*)&Vt[d*16 + la][ks*32 + kg*8];
          Oacc[d] = mfma16(pa, vb, Oacc[d]);
        }
      }
    }

    // finalize
    #pragma unroll
    for (int d = 0; d < 4; d++)
      #pragma unroll
      for (int r = 0; r < 4; r++){
        float v = Oacc[d][r] / l[r];
        long row = (long)(b*SEQ + qbase + w*16 + kg*4 + r);
        attout[row*DIMN + h*64 + d*16 + la] = f2bf(v);
      }
  }
}

// ---------------- host ----------------
extern "C" void kernel_launch(void* const* d_in, const int* in_sizes, int n_in,
                              void* d_out, int out_size, void* d_ws, size_t ws_size,
                              hipStream_t stream){
  const float* x  = (const float*)d_in[0];
  const float* wq = (const float*)d_in[1];
  const float* wk = (const float*)d_in[2];
  const float* wv = (const float*)d_in[3];
  const float* wo = (const float*)d_in[4];
  float* out = (float*)d_out;
  char* ws = (char*)d_ws;

  const size_t SZ_QD = (size_t)ROWS*DIMN*2;  // 16 MB
  const size_t SZ_KD = (size_t)ROWS*KVD*2;   // 4 MB
  const size_t NEED = 65536 + 3*SZ_QD + 3*SZ_KD;
  if (ws_size < NEED) return;

  float* scales   = (float*)ws;
  float* partials = (float*)(ws + 1024);
  size_t off = 65536;
  auto alloc = [&](size_t bytes)->char*{
    char* p = ws + off; off += (bytes + 255) & ~(size_t)255; return p;
  };
  short* qhib = (short*)alloc(SZ_QD);
  short* qlob = (short*)alloc(SZ_QD);
  short* khib = (short*)alloc(SZ_KD);
  short* klob = (short*)alloc(SZ_KD);
  short* vhib = (short*)alloc(SZ_KD);
  short* atto = (short*)alloc(SZ_QD);

  // 1) weight thresholds
  {
    dim3 g(256, 4);
    k_abssum4<<<g,256,0,stream>>>(wq, wk, wv, wo, partials);
  }
  k_scales<<<1,256,0,stream>>>(partials, scales);

  // 2) Q/K/V GEMMs (x split + W ternarize fused into staging)
  {
    dim3 g(DIMN/128, ROWS/128);
    k_gemm_qkv<1><<<g,256,0,stream>>>(x, wq, scales, 0, qhib, qlob, ROWS, DIMN, DIMN);
  }
  {
    dim3 g(KVD/128, ROWS/128);
    k_gemm_qkv<1><<<g,256,0,stream>>>(x, wk, scales, 1, khib, klob, ROWS, KVD, DIMN);
    k_gemm_qkv<0><<<g,256,0,stream>>>(x, wv, scales, 2, vhib, nullptr, ROWS, KVD, DIMN);
  }

  // 3) attention (balanced causal pairing)
  {
    dim3 g(NT/2, NH, BATCH);
    k_attn<<<g,256,0,stream>>>(qhib, qlob, khib, klob, vhib, atto);
  }

  // 4) output GEMM -> f32
  {
    dim3 g(DIMN/128, ROWS/128);
    k_gemm_out<<<g,256,0,stream>>>(atto, wo, scales, 3, out, ROWS, DIMN, DIMN);
  }
}